// Round 9
// baseline (86.178 us; speedup 1.0000x reference)
//
#include <hip/hip_runtime.h>

#define TT 1024
#define HH 8
#define EE 64
#define MM 128
#define NBH 16

#define NORMALIZER 0.35355339059327379f
#define RSQRT_M    0.08838834764831845f
#define TEMP       0.125f
#define NEGINF     -1e24f

typedef __attribute__((ext_vector_type(8))) short short8v;
typedef __attribute__((ext_vector_type(4))) float f32x4;
#define MFMA_BF16 __builtin_amdgcn_mfma_f32_16x16x32_bf16

// ws byte offsets (all bf16 planes are hi/lo pairs)
#define OFF_QPH   0u          // [16][1024][128] short  4 MB  q' scaled, hi
#define OFF_QPL   4194304u
#define OFF_KPH   8388608u    // [16][1024][128] short  4 MB  exp(lf_k) RAW, hi
#define OFF_KPL   12582912u
#define OFF_Q16H  16777216u   // [16][1024][64]  short  2 MB
#define OFF_Q16L  18874368u
#define OFF_K16H  20971520u
#define OFF_K16L  23068672u
#define OFF_VTH   25165824u   // [16][64][1024]  short  2 MB  (V transposed)
#define OFF_VTL   27262976u
#define OFF_KVP   29360128u   // [256][128][64]  f32    8 MB  unscaled kv partials
#define OFF_KSUMP 37748736u   // [256][128]      f32  128 KB
#define OFF_WTMAX 37879808u   // [16][16]        f32    1 KB
#define OFF_QSTAB 37880832u   // [16][1024]      f32   64 KB  (ends 37946368)
#define OFF_KVT_H 37946368u   // [16][66][128]   short 264 KB (rows 64/65 = ksum hi/lo)
#define OFF_KVT_L 38216704u   //                        (ends 38487040)

__device__ __forceinline__ unsigned short f2bf(float x) {
  unsigned u = __float_as_uint(x);
  u += 0x7FFFu + ((u >> 16) & 1u);
  return (unsigned short)(u >> 16);
}
__device__ __forceinline__ float bf2f(unsigned short h) {
  return __uint_as_float(((unsigned)h) << 16);
}
__device__ __forceinline__ void f2bf2(float x, unsigned short& hi, unsigned short& lo) {
  hi = f2bf(x);
  lo = f2bf(x - bf2f(hi));
}
// MFMA A/B fragment load from row-major [row][K] bf16 (LDS or global).
__device__ __forceinline__ short8v ldfrag(const short* buf, int ld, int rowbase,
                                          int kbase, int lane) {
  return *(const short8v*)&buf[(size_t)(rowbase + (lane & 15)) * ld + kbase + ((lane >> 4) << 3)];
}

// ---------------------------------------------------------------------------
// Kernel A: FAVOR+ features + (k-path) fused kv-partial + vT16 planes.
// Grid 512; path = bid&1 (interleaved so CUs get one q + one k block).
// ---------------------------------------------------------------------------
__global__ __launch_bounds__(256, 2) void feat_kernel(
    const float* __restrict__ Q, const float* __restrict__ K,
    const float* __restrict__ V, const float* __restrict__ proj,
    char* __restrict__ ws)
{
  __shared__ float xsT[64][65];   // [e][row]
  __shared__ float Mh[64][4];
  __shared__ __align__(16) float smem2[64 * 132 + 64 * 68];  // k-path: kp_s, vs, kvm

  const int bid  = blockIdx.x;
  const int path = bid & 1;           // 0=q, 1=k
  const int rest = bid >> 1;          // 0..255
  const int bh   = rest >> 4;
  const int rt   = rest & 15;
  const int b = bh >> 3, h = bh & 7;
  const int t0 = rt << 6;
  const int tid = threadIdx.x;

  const float* x = path ? K : Q;
  const float* xbase = x + (((size_t)b * TT * HH + h) << 6);
#pragma unroll
  for (int it = 0; it < 4; ++it) {
    const int idx = (it << 8) + tid;
    const int r = idx >> 4, c = (idx & 15) << 2;
    const float4 f4 = *(const float4*)&xbase[(size_t)(t0 + r) * 512 + c];
    xsT[c + 0][r] = f4.x; xsT[c + 1][r] = f4.y;
    xsT[c + 2][r] = f4.z; xsT[c + 3][r] = f4.w;
  }
  __syncthreads();

  const int lane = tid & 63;
  const int w = __builtin_amdgcn_readfirstlane(tid >> 6);
  float xv[64];
  float diag = 0.f;
#pragma unroll
  for (int c = 0; c < 64; ++c) { xv[c] = xsT[c][lane]; diag = fmaf(xv[c], xv[c], diag); }
  diag *= 0.0625f;   // 0.5*temp

  float lf[32];
  float mx = -3e30f;
  const int mbase = w << 5;
  for (int mm = 0; mm < 32; ++mm) {
    const float* pr = proj + ((mbase + mm) << 6);
    float a0 = 0.f, a1 = 0.f;
#pragma unroll
    for (int c = 0; c < 64; c += 2) {
      a0 = fmaf(xv[c], pr[c], a0);
      a1 = fmaf(xv[c + 1], pr[c + 1], a1);
    }
    const float v = fmaf(NORMALIZER, a0 + a1, -diag);
    lf[mm] = v;
    mx = fmaxf(mx, v);
  }
  Mh[lane][w] = mx;
  __syncthreads();
  const float m0 = fmaxf(fmaxf(Mh[lane][0], Mh[lane][1]), fmaxf(Mh[lane][2], Mh[lane][3]));

  float ov[32];
  if (path == 0) {
#pragma unroll
    for (int mm = 0; mm < 32; ++mm) ov[mm] = RSQRT_M * __expf(lf[mm] - m0);
    if (w == 0) ((float*)(ws + OFF_QSTAB))[(size_t)bh * TT + t0 + lane] = m0;
  } else {
#pragma unroll
    for (int mm = 0; mm < 32; ++mm) ov[mm] = __expf(lf[mm]);
    if (w == 0) {
      float bm = m0;
#pragma unroll
      for (int off = 1; off < 64; off <<= 1) bm = fmaxf(bm, __shfl_xor(bm, off));
      if (lane == 0) ((float*)(ws + OFF_WTMAX))[(bh << 4) + rt] = bm;
    }
  }

  // feature planes hi/lo
  {
    short* fh = (short*)(ws + (path ? OFF_KPH : OFF_QPH)) +
                (((size_t)bh * TT + t0 + lane) << 7) + mbase;
    short* fl = (short*)(ws + (path ? OFF_KPL : OFF_QPL)) +
                (((size_t)bh * TT + t0 + lane) << 7) + mbase;
#pragma unroll
    for (int q4 = 0; q4 < 8; ++q4) {
      short4 h4, l4;
      f2bf2(ov[q4 * 4 + 0], (unsigned short&)h4.x, (unsigned short&)l4.x);
      f2bf2(ov[q4 * 4 + 1], (unsigned short&)h4.y, (unsigned short&)l4.y);
      f2bf2(ov[q4 * 4 + 2], (unsigned short&)h4.z, (unsigned short&)l4.z);
      f2bf2(ov[q4 * 4 + 3], (unsigned short&)h4.w, (unsigned short&)l4.w);
      *(short4*)&fh[q4 << 2] = h4;
      *(short4*)&fl[q4 << 2] = l4;
    }
  }

  // x16 planes hi/lo from xsT (coalesced: 8 threads cover one row)
  {
    short* xh = (short*)(ws + (path ? OFF_K16H : OFF_Q16H)) + ((size_t)bh * TT + t0) * 64;
    short* xl = (short*)(ws + (path ? OFF_K16L : OFF_Q16L)) + ((size_t)bh * TT + t0) * 64;
#pragma unroll
    for (int it = 0; it < 2; ++it) {
      const int gg = (it << 8) + tid;
      const int r = gg >> 3, c8 = (gg & 7) << 3;
      short4 h0, h1, l0, l1;
      f2bf2(xsT[c8 + 0][r], (unsigned short&)h0.x, (unsigned short&)l0.x);
      f2bf2(xsT[c8 + 1][r], (unsigned short&)h0.y, (unsigned short&)l0.y);
      f2bf2(xsT[c8 + 2][r], (unsigned short&)h0.z, (unsigned short&)l0.z);
      f2bf2(xsT[c8 + 3][r], (unsigned short&)h0.w, (unsigned short&)l0.w);
      f2bf2(xsT[c8 + 4][r], (unsigned short&)h1.x, (unsigned short&)l1.x);
      f2bf2(xsT[c8 + 5][r], (unsigned short&)h1.y, (unsigned short&)l1.y);
      f2bf2(xsT[c8 + 6][r], (unsigned short&)h1.z, (unsigned short&)l1.z);
      f2bf2(xsT[c8 + 7][r], (unsigned short&)h1.w, (unsigned short&)l1.w);
      *(short4*)&xh[r * 64 + c8 + 0] = h0;
      *(short4*)&xh[r * 64 + c8 + 4] = h1;
      *(short4*)&xl[r * 64 + c8 + 0] = l0;
      *(short4*)&xl[r * 64 + c8 + 4] = l1;
    }
  }

  if (path == 0) return;

  // ================= k-path: fused kv_partial + vT16 =================
  float (*kp_s)[132] = (float(*)[132])smem2;
  float (*vs)[68] = (float(*)[68])(smem2 + 64 * 132);

  // k' (raw f32) -> LDS; lane owns row `lane`, wave owns m-range mbase
#pragma unroll
  for (int q4 = 0; q4 < 8; ++q4)
    *(float4*)&kp_s[lane][mbase + (q4 << 2)] =
        make_float4(ov[q4 * 4], ov[q4 * 4 + 1], ov[q4 * 4 + 2], ov[q4 * 4 + 3]);

  // V rows t0..t0+63
  const float* Vbase = V + (((size_t)b * TT * HH + h) << 6);
#pragma unroll
  for (int it = 0; it < 4; ++it) {
    const int idx = (it << 10) + (tid << 2);
    const int r = idx >> 6, c = idx & 63;
    *(float4*)&vs[r][c] = *(const float4*)&Vbase[(size_t)(t0 + r) * 512 + c];
  }
  __syncthreads();

  // ksum partial
  if (tid < 128) {
    float s = 0.f;
    for (int ss = 0; ss < 64; ++ss) s += kp_s[ss][tid];
    ((float*)(ws + OFF_KSUMP))[(rest << 7) + tid] = s;
  }

  // kv partial: acc[8 m][8 d], two 32-row halves
  const int h2 = tid >> 7;
  const int m0i = ((tid & 127) >> 3) << 3;
  const int d0 = (tid & 7) << 3;
  float acc[8][8];
#pragma unroll
  for (int i = 0; i < 8; ++i)
#pragma unroll
    for (int j = 0; j < 8; ++j) acc[i][j] = 0.f;
  const int s0 = h2 << 5;
  for (int ss = s0; ss < s0 + 32; ++ss) {
    const float4 k0v = *(const float4*)&kp_s[ss][m0i];
    const float4 k1v = *(const float4*)&kp_s[ss][m0i + 4];
    const float4 v0v = *(const float4*)&vs[ss][d0];
    const float4 v1v = *(const float4*)&vs[ss][d0 + 4];
    const float km[8] = {k0v.x,k0v.y,k0v.z,k0v.w,k1v.x,k1v.y,k1v.z,k1v.w};
    const float vd[8] = {v0v.x,v0v.y,v0v.z,v0v.w,v1v.x,v1v.y,v1v.z,v1v.w};
#pragma unroll
    for (int i = 0; i < 8; ++i)
#pragma unroll
      for (int j = 0; j < 8; ++j) acc[i][j] = fmaf(km[i], vd[j], acc[i][j]);
  }

  // vT16 planes (reads vs — before kvm overlay clobbers it)
  {
    short* vh = (short*)(ws + OFF_VTH) + (size_t)bh * 64 * TT;
    short* vl = (short*)(ws + OFF_VTL) + (size_t)bh * 64 * TT;
    const int d = tid >> 2, jg = (tid & 3) << 4;
#pragma unroll
    for (int j0 = 0; j0 < 16; j0 += 4) {
      short4 h4, l4;
      f2bf2(vs[jg + j0 + 0][d], (unsigned short&)h4.x, (unsigned short&)l4.x);
      f2bf2(vs[jg + j0 + 1][d], (unsigned short&)h4.y, (unsigned short&)l4.y);
      f2bf2(vs[jg + j0 + 2][d], (unsigned short&)h4.z, (unsigned short&)l4.z);
      f2bf2(vs[jg + j0 + 3][d], (unsigned short&)h4.w, (unsigned short&)l4.w);
      *(short4*)&vh[(size_t)d * TT + t0 + jg + j0] = h4;
      *(short4*)&vl[(size_t)d * TT + t0 + jg + j0] = l4;
    }
  }
  __syncthreads();

  // merge halves via LDS overlay, then plain f32 partial stores
  float (*kvm)[68] = (float(*)[68])smem2;
  if (h2 == 0) {
#pragma unroll
    for (int i = 0; i < 8; ++i)
#pragma unroll
      for (int j = 0; j < 8; ++j) kvm[m0i + i][d0 + j] = acc[i][j];
  }
  __syncthreads();
  if (h2 == 1) {
#pragma unroll
    for (int i = 0; i < 8; ++i)
#pragma unroll
      for (int j = 0; j < 8; ++j) kvm[m0i + i][d0 + j] += acc[i][j];
  }
  __syncthreads();
  float* kvb = (float*)(ws + OFF_KVP) + ((size_t)rest << 13);
#pragma unroll
  for (int it = 0; it < 8; ++it) {
    const int idx = (it << 10) + (tid << 2);
    const int m = idx >> 6, d = idx & 63;
    *(float4*)&kvb[idx] = make_float4(kvm[m][d], kvm[m][d + 1], kvm[m][d + 2], kvm[m][d + 3]);
  }
}

// ---------------------------------------------------------------------------
// Kernel B2: reduce 16 kv partials, scale, emit transposed kvT bf16 hi/lo
// [66][128] per bh (rows 64/65 = ksum hi/lo; lo-plane rows 64/65 = 0).
// Grid 16 (one block per bh).
// ---------------------------------------------------------------------------
__global__ __launch_bounds__(256, 2) void kv_reduce(char* __restrict__ ws)
{
  __shared__ float kvT_s[64 * 130];
  const int bh = blockIdx.x;
  const int tid = threadIdx.x;
  const float* wtmax = (const float*)(ws + OFF_WTMAX);
  float kml = wtmax[bh << 4];
#pragma unroll
  for (int i = 1; i < 16; ++i) kml = fmaxf(kml, wtmax[(bh << 4) + i]);
  const float scale = RSQRT_M * __expf(-kml);

  const float* kvp = (const float*)(ws + OFF_KVP);
  const int m = tid >> 1, dh = (tid & 1) << 5;
  float s[32];
#pragma unroll
  for (int i = 0; i < 32; ++i) s[i] = 0.f;
#pragma unroll
  for (int p = 0; p < 16; ++p) {
    const float* base = kvp + ((((size_t)(bh << 4) + p) << 13) | ((size_t)m << 6)) + dh;
#pragma unroll
    for (int i = 0; i < 8; ++i) {
      const float4 v = *(const float4*)&base[i << 2];
      s[i * 4 + 0] += v.x; s[i * 4 + 1] += v.y; s[i * 4 + 2] += v.z; s[i * 4 + 3] += v.w;
    }
  }
#pragma unroll
  for (int i = 0; i < 32; ++i) kvT_s[(dh + i) * 130 + m] = s[i] * scale;

  // ksum reduce (value held across barrier)
  float ks = 0.f;
  if (tid < 128) {
    const float* ksump = (const float*)(ws + OFF_KSUMP);
#pragma unroll
    for (int p = 0; p < 16; ++p) ks += ksump[(((bh << 4) + p) << 7) + tid];
    ks *= scale;
  }
  __syncthreads();

  short* kh = (short*)(ws + OFF_KVT_H) + (size_t)bh * 66 * 128;
  short* kl = (short*)(ws + OFF_KVT_L) + (size_t)bh * 66 * 128;
  const int d = tid >> 2, mg = (tid & 3) << 5;
#pragma unroll
  for (int j0 = 0; j0 < 32; j0 += 4) {
    short4 h4, l4;
    f2bf2(kvT_s[d * 130 + mg + j0 + 0], (unsigned short&)h4.x, (unsigned short&)l4.x);
    f2bf2(kvT_s[d * 130 + mg + j0 + 1], (unsigned short&)h4.y, (unsigned short&)l4.y);
    f2bf2(kvT_s[d * 130 + mg + j0 + 2], (unsigned short&)h4.z, (unsigned short&)l4.z);
    f2bf2(kvT_s[d * 130 + mg + j0 + 3], (unsigned short&)h4.w, (unsigned short&)l4.w);
    *(short4*)&kh[d * 128 + mg + j0] = h4;
    *(short4*)&kl[d * 128 + mg + j0] = l4;
  }
  if (tid < 128) {
    unsigned short hs, ls;
    f2bf2(ks, hs, ls);
    kh[64 * 128 + tid] = hs;
    kh[65 * 128 + tid] = ls;
    kl[64 * 128 + tid] = 0;
    kl[65 * 128 + tid] = 0;
  }
}

// ---------------------------------------------------------------------------
// Kernel D: banded local attention, double-bf16 MFMA, copy-only staging.
// Grid 256 = 16 bh * 16 tiles(64 q, window 128). ~70 KB LDS.
// A-fragments read directly from global planes (per-wave private rows).
// ---------------------------------------------------------------------------
__global__ __launch_bounds__(256, 2) void band_kernel(
    char* __restrict__ ws, float* __restrict__ out)
{
  __shared__ __align__(16) short smem[34816];
  __shared__ float pls_s[64];
  // phase AB
  short* const B_hi   = smem;           // [128][72]
  short* const B_lo   = smem + 9216;
  short* const kvT_hi = smem + 18432;   // [80][72] (rows 66-79 unused)
  short* const kvT_lo = smem + 24192;
  // phase C overlay
  short* const VT_hi   = smem;          // [64][136]
  short* const VT_lo   = smem + 8704;
  short* const dots_hi = smem + 17408;  // [64][136]
  short* const dots_lo = smem + 26112;

  const int g = blockIdx.x;
  const int lg = ((g & 7) << 5) | (g >> 3);          // XCD chunk swizzle
  const int bh = lg >> 4, tile = lg & 15;
  const int b = bh >> 3, h = bh & 7;
  const int t0 = tile << 6;
  const int k0 = t0 - 32;
  const int tid = threadIdx.x;
  const int lane = tid & 63;
  const int wq = __builtin_amdgcn_readfirstlane(tid >> 6);

  const float* wtmax = (const float*)(ws + OFF_WTMAX);
  float kml = wtmax[bh << 4];
#pragma unroll
  for (int i = 1; i < 16; ++i) kml = fmaxf(kml, wtmax[(bh << 4) + i]);
  const float kscale = RSQRT_M * __expf(-kml);

  const short* q16h = (const short*)(ws + OFF_Q16H) + ((size_t)bh * TT + t0) * 64;
  const short* q16l = (const short*)(ws + OFF_Q16L) + ((size_t)bh * TT + t0) * 64;
  const short* qph  = (const short*)(ws + OFF_QPH) + (((size_t)bh * TT + t0) << 7);
  const short* qpl  = (const short*)(ws + OFF_QPL) + (((size_t)bh * TT + t0) << 7);
  const short* k16h = (const short*)(ws + OFF_K16H) + (size_t)bh * TT * 64;
  const short* k16l = (const short*)(ws + OFF_K16L) + (size_t)bh * TT * 64;
  const short* kphg = (const short*)(ws + OFF_KPH) + ((size_t)bh * TT << 7);
  const short* kplg = (const short*)(ws + OFF_KPL) + ((size_t)bh * TT << 7);
  const short* kvth = (const short*)(ws + OFF_KVT_H) + (size_t)bh * 66 * 128;
  const short* kvtl = (const short*)(ws + OFF_KVT_L) + (size_t)bh * 66 * 128;
  const short* vth  = (const short*)(ws + OFF_VTH) + (size_t)bh * 64 * TT;
  const short* vtl  = (const short*)(ws + OFF_VTL) + (size_t)bh * 64 * TT;

  if (tid < 64)
    pls_s[tid] = ((const float*)(ws + OFF_QSTAB))[(size_t)bh * TT + t0 + tid] + kml;

  // ---- stage B = k16 window (128 x 64), hi/lo ----
#pragma unroll
  for (int it = 0; it < 8; ++it) {
    const int gg = (it << 8) + tid;
    const int r = gg >> 4, c4 = (gg & 15) << 2;
    const int tg = min(max(k0 + r, 0), TT - 1);
    *(short4*)&B_hi[r * 72 + c4] = *(const short4*)&k16h[(size_t)tg * 64 + c4];
    *(short4*)&B_lo[r * 72 + c4] = *(const short4*)&k16l[(size_t)tg * 64 + c4];
  }
  __syncthreads();

  // ---- GEMM1: S = q . K^T (3-product) ----
  f32x4 C1[8];
#pragma unroll
  for (int nt = 0; nt < 8; ++nt) C1[nt] = (f32x4){0.f, 0.f, 0.f, 0.f};
  {
    const short8v qh0 = ldfrag(q16h, 64, wq << 4, 0, lane);
    const short8v qh1 = ldfrag(q16h, 64, wq << 4, 32, lane);
    const short8v ql0 = ldfrag(q16l, 64, wq << 4, 0, lane);
    const short8v ql1 = ldfrag(q16l, 64, wq << 4, 32, lane);
#pragma unroll
    for (int nt = 0; nt < 8; ++nt) {
      const short8v bh0 = ldfrag(B_hi, 72, nt << 4, 0, lane);
      const short8v bh1 = ldfrag(B_hi, 72, nt << 4, 32, lane);
      C1[nt] = MFMA_BF16(qh0, bh0, C1[nt], 0, 0, 0);
      C1[nt] = MFMA_BF16(qh1, bh1, C1[nt], 0, 0, 0);
      C1[nt] = MFMA_BF16(qh0, ldfrag(B_lo, 72, nt << 4, 0, lane), C1[nt], 0, 0, 0);
      C1[nt] = MFMA_BF16(qh1, ldfrag(B_lo, 72, nt << 4, 32, lane), C1[nt], 0, 0, 0);
      C1[nt] = MFMA_BF16(ql0, bh0, C1[nt], 0, 0, 0);
      C1[nt] = MFMA_BF16(ql1, bh1, C1[nt], 0, 0, 0);
    }
  }

  // ---- GEMM2 (q'.kp^T) + C3 (q'.kvT + qk1), two 64-m chunks ----
  f32x4 C2[8], C3[5];
#pragma unroll
  for (int nt = 0; nt < 8; ++nt) C2[nt] = (f32x4){0.f, 0.f, 0.f, 0.f};
#pragma unroll
  for (int nt = 0; nt < 5; ++nt) C3[nt] = (f32x4){0.f, 0.f, 0.f, 0.f};

#pragma unroll 1
  for (int c = 0; c < 2; ++c) {
    const int co = c << 6;
    __syncthreads();   // previous B/kvT consumers done
    // kp window chunk
#pragma unroll
    for (int it = 0; it < 8; ++it) {
      const int gg = (it << 8) + tid;
      const int r = gg >> 4, c4 = (gg & 15) << 2;
      const int tg = min(max(k0 + r, 0), TT - 1);
      *(short4*)&B_hi[r * 72 + c4] = *(const short4*)&kphg[((size_t)tg << 7) + co + c4];
      *(short4*)&B_lo[r * 72 + c4] = *(const short4*)&kplg[((size_t)tg << 7) + co + c4];
    }
    // kvT chunk (rows 0..63 = d, cols co..co+63)
#pragma unroll
    for (int it = 0; it < 4; ++it) {
      const int gg = (it << 8) + tid;
      const int r = gg >> 4, c4 = (gg & 15) << 2;
      *(short4*)&kvT_hi[r * 72 + c4] = *(const short4*)&kvth[(size_t)r * 128 + co + c4];
      *(short4*)&kvT_lo[r * 72 + c4] = *(const short4*)&kvtl[(size_t)r * 128 + co + c4];
    }
    if (tid < 128) {  // ksum rows 64/65
      const int r = 64 + (tid >> 6), mm = tid & 63;
      kvT_hi[r * 72 + mm] = kvth[(size_t)r * 128 + co + mm];
      kvT_lo[r * 72 + mm] = 0;
    }
    __syncthreads();

    const short8v ph0 = ldfrag(qph, 128, wq << 4, co + 0, lane);
    const short8v ph1 = ldfrag(qph, 128, wq << 4, co + 32, lane);
    const short8v pl0 = ldfrag(qpl, 128, wq << 4, co + 0, lane);
    const short8v pl1 = ldfrag(qpl, 128, wq << 4, co + 32, lane);
#pragma unroll
    for (int nt = 0; nt < 8; ++nt) {
      const short8v bh0 = ldfrag(B_hi, 72, nt << 4, 0, lane);
      const short8v bh1 = ldfrag(B_hi, 72, nt << 4, 32, lane);
      C2[nt] = MFMA_BF16(ph0, bh0, C2[nt], 0, 0, 0);
      C2[nt] = MFMA_BF16(ph1, bh1, C2[nt], 0, 0, 0);
      C2[nt] = MFMA_BF16(ph0, ldfrag(B_lo, 72, nt << 4, 0, lane), C2[nt], 0, 0, 0);
      C2[nt] = MFMA_BF16(ph1, ldfrag(B_lo, 72, nt << 4, 32, lane), C2[nt], 0, 0, 0);
      C2[nt] = MFMA_BF16(pl0, bh0, C2[nt], 0, 0, 0);
      C2[nt] = MFMA_BF16(pl1, bh1, C2[nt], 0, 0, 0);
    }
#pragma unroll
    for (int nt = 0; nt < 5; ++nt) {
      const short8v kh0 = ldfrag(kvT_hi, 72, nt << 4, 0, lane);
      const short8v kh1 = ldfrag(kvT_hi, 72, nt << 4, 32, lane);
      C3[nt] = MFMA_BF16(ph0, kh0, C3[nt], 0, 0, 0);
      C3[nt] = MFMA_BF16(ph1, kh1, C3[nt], 0, 0, 0);
      C3[nt] = MFMA_BF16(ph0, ldfrag(kvT_lo, 72, nt << 4, 0, lane), C3[nt], 0, 0, 0);
      C3[nt] = MFMA_BF16(ph1, ldfrag(kvT_lo, 72, nt << 4, 32, lane), C3[nt], 0, 0, 0);
      C3[nt] = MFMA_BF16(pl0, kh0, C3[nt], 0, 0, 0);
      C3[nt] = MFMA_BF16(pl1, kh1, C3[nt], 0, 0, 0);
    }
  }
  __syncthreads();   // B/kvT done; VT overlays them

  // ---- Phase C: copy V^T window (64 d x 128 j), hi/lo, col-clamped ----
#pragma unroll
  for (int it = 0; it < 8; ++it) {
    const int gg = (it << 8) + tid;
    const int d = gg >> 5, j4 = (gg & 31) << 2;
    const int jj = k0 + j4;
    short4 h4, l4;
    if (jj >= 0 && jj <= TT - 4) {
      h4 = *(const short4*)&vth[(size_t)d * TT + jj];
      l4 = *(const short4*)&vtl[(size_t)d * TT + jj];
    } else {
      const int j0c = min(max(jj + 0, 0), TT - 1);
      const int j1c = min(max(jj + 1, 0), TT - 1);
      const int j2c = min(max(jj + 2, 0), TT - 1);
      const int j3c = min(max(jj + 3, 0), TT - 1);
      h4.x = vth[(size_t)d * TT + j0c]; l4.x = vtl[(size_t)d * TT + j0c];
      h4.y = vth[(size_t)d * TT + j1c]; l4.y = vtl[(size_t)d * TT + j1c];
      h4.z = vth[(size_t)d * TT + j2c]; l4.z = vtl[(size_t)d * TT + j2c];
      h4.w = vth[(size_t)d * TT + j3c]; l4.w = vtl[(size_t)d * TT + j3c];
    }
    *(short4*)&VT_hi[d * 136 + j4] = h4;
    *(short4*)&VT_lo[d * 136 + j4] = l4;
  }

  // ---- P3: per-lane softmax / log-norm, dots hi/lo -> LDS ----
  float psr[4];
  const int lrow = (lane >> 4) << 2;
  const int lcol = lane & 15;
#pragma unroll
  for (int r = 0; r < 4; ++r) {
    const int ql = (wq << 4) + lrow + r;
    float qkt[8], dpt[8];
    float mx = -3e30f;
#pragma unroll
    for (int nt = 0; nt < 8; ++nt) {
      const int kr = (nt << 4) + lcol;
      const int j = kr - ql;
      const int gk = k0 + kr;
      const bool vv = (j >= 0) && (j < 64) && (gk >= 0) && (gk < TT);
      qkt[nt] = vv ? TEMP * C1[nt][r] : NEGINF;
      dpt[nt] = vv ? kscale * C2[nt][r] : 0.f;
      mx = fmaxf(mx, qkt[nt]);
    }
    mx = fmaxf(mx, __shfl_xor(mx, 1));
    mx = fmaxf(mx, __shfl_xor(mx, 2));
    mx = fmaxf(mx, __shfl_xor(mx, 4));
    mx = fmaxf(mx, __shfl_xor(mx, 8));
    float se = 0.f, dps = 0.f;
#pragma unroll
    for (int nt = 0; nt < 8; ++nt) {
      se += __expf(qkt[nt] - mx);
      dps += dpt[nt];
    }
    se += __shfl_xor(se, 1); se += __shfl_xor(se, 2);
    se += __shfl_xor(se, 4); se += __shfl_xor(se, 8);
    dps += __shfl_xor(dps, 1); dps += __shfl_xor(dps, 2);
    dps += __shfl_xor(dps, 4); dps += __shfl_xor(dps, 8);
    const float qk1 = __shfl(C3[4][r], lane & 48) + __shfl(C3[4][r], (lane & 48) + 1);

    const float pls = pls_s[ql];
    const float lse = mx + __logf(se);
    const float lr = fmaxf(qk1 - dps, 1e-24f);
    const float lrl = __logf(lr) + pls;
    const float aa = fmaxf(lse, lrl), bb = fminf(lse, lrl);
    const float ln = aa + log1pf(__expf(bb - aa));
    psr[r] = __expf(pls - ln);
#pragma unroll
    for (int nt = 0; nt < 8; ++nt) {
      const float d = __expf(qkt[nt] - ln) - dpt[nt] * psr[r];
      unsigned short hs, ls;
      f2bf2(d, hs, ls);
      dots_hi[ql * 136 + (nt << 4) + lcol] = hs;
      dots_lo[ql * 136 + (nt << 4) + lcol] = ls;
    }
  }
  __syncthreads();

  // ---- PV: out_local = dots . V (3-product) + qkv * ps epilogue ----
  f32x4 D4[4];
#pragma unroll
  for (int nt = 0; nt < 4; ++nt) D4[nt] = (f32x4){0.f, 0.f, 0.f, 0.f};
#pragma unroll
  for (int kk = 0; kk < 4; ++kk) {
    const short8v adh = ldfrag(dots_hi, 136, wq << 4, kk << 5, lane);
    const short8v adl = ldfrag(dots_lo, 136, wq << 4, kk << 5, lane);
#pragma unroll
    for (int nt = 0; nt < 4; ++nt) {
      const short8v vh = ldfrag(VT_hi, 136, nt << 4, kk << 5, lane);
      D4[nt] = MFMA_BF16(adh, vh, D4[nt], 0, 0, 0);
      D4[nt] = MFMA_BF16(adh, ldfrag(VT_lo, 136, nt << 4, kk << 5, lane), D4[nt], 0, 0, 0);
      D4[nt] = MFMA_BF16(adl, vh, D4[nt], 0, 0, 0);
    }
  }
#pragma unroll
  for (int nt = 0; nt < 4; ++nt) {
#pragma unroll
    for (int r = 0; r < 4; ++r) {
      const int ql = (wq << 4) + lrow + r;
      const float val = D4[nt][r] + C3[nt][r] * psr[r];
      out[((((size_t)b * TT + t0 + ql) * HH + h) << 6) + (nt << 4) + lcol] = val;
    }
  }
}

extern "C" void kernel_launch(void* const* d_in, const int* in_sizes, int n_in,
                              void* d_out, int out_size, void* d_ws, size_t ws_size,
                              hipStream_t stream) {
  (void)in_sizes; (void)n_in; (void)out_size; (void)ws_size;
  const float* Q    = (const float*)d_in[0];
  const float* K    = (const float*)d_in[1];
  const float* V    = (const float*)d_in[2];
  const float* proj = (const float*)d_in[3];
  float* out = (float*)d_out;
  char* ws = (char*)d_ws;

  feat_kernel<<<512, 256, 0, stream>>>(Q, K, V, proj, ws);
  kv_reduce<<<16, 256, 0, stream>>>(ws);
  band_kernel<<<256, 256, 0, stream>>>(ws, out);
}

// Round 10
// 58.742 us; speedup vs baseline: 1.4671x; 1.4671x over previous
//
#include <hip/hip_runtime.h>

#define TT 1024
#define HH 8
#define EE 64
#define MM 128
#define NBH 16

#define NORMALIZER 0.35355339059327379f
#define RSQRT_M    0.08838834764831845f
#define TEMP       0.125f
#define NEGINF     -1e24f

typedef __attribute__((ext_vector_type(8))) short short8v;
typedef __attribute__((ext_vector_type(4))) float f32x4;
#define MFMA_BF16 __builtin_amdgcn_mfma_f32_16x16x32_bf16

// ws byte offsets
#define OFF_QP    0u            // [BH][T][M] f32  8 MB   q_prime (scaled)
#define OFF_KF    8388608u      // [BH][T][M] f32  8 MB   exp(logfeat_k) RAW
#define OFF_KVP   16777216u     // [BH][16][M][E] f32 8 MB unscaled kv partials
#define OFF_KV    25165824u     // [BH][M][E] f32  512 KB (scaled)
#define OFF_KSUM  25690112u     // [BH][M]    f32  8 KB   (scaled)
#define OFF_QSTAB 25698304u     // [BH][T]    f32  64 KB
#define OFF_KSUMP 25763840u     // [BH][16][M] f32 128 KB (unscaled partials)
#define OFF_WTMAX 25894912u     // [BH][16]   f32  1 KB   per-tile k logfeat max

__device__ __forceinline__ unsigned short f2bf(float x) {
  unsigned u = __float_as_uint(x);
  u += 0x7FFFu + ((u >> 16) & 1u);
  return (unsigned short)(u >> 16);
}
__device__ __forceinline__ float bf2f(unsigned short h) {
  return __uint_as_float(((unsigned)h) << 16);
}
__device__ __forceinline__ void f2bf2(float x, unsigned short& hi, unsigned short& lo) {
  hi = f2bf(x);
  lo = f2bf(x - bf2f(hi));
}
// MFMA A/B fragment load: row-major [row][K] bf16 buffer, LD in elems.
__device__ __forceinline__ short8v ldfrag(const short* buf, int ld, int rowbase,
                                          int kbase, int lane) {
  return *(const short8v*)&buf[(rowbase + (lane & 15)) * ld + kbase + ((lane >> 4) << 3)];
}

// ---------------------------------------------------------------------------
// Kernel A: FAVOR+ features. Grid 512 = 2 paths * 16 bh * 16 rowtiles(64),
// BLOCK 512 (8 waves): wave w owns wave-uniform m-slice [w*16, w*16+16) ->
// scalar proj loads; per-thread state xv[64]+lf[16]+ov[16] (no spill).
// Row max crosses 8 waves via Mh[64][8]. ~17 KB LDS.
// ---------------------------------------------------------------------------
__global__ __launch_bounds__(512, 2) void feat_kernel(
    const float* __restrict__ Q, const float* __restrict__ K,
    const float* __restrict__ proj,
    float* __restrict__ qp, float* __restrict__ kf,
    float* __restrict__ qstab, float* __restrict__ wtmax)
{
  __shared__ float xsT[64][65];   // [e][row]
  __shared__ float Mh[64][8];

  const int bid  = blockIdx.x;
  const int path = bid >> 8;          // 0=q, 1=k
  const int bh   = (bid >> 4) & 15;
  const int rt   = bid & 15;
  const int b = bh >> 3, h = bh & 7;
  const int t0 = rt << 6;
  const int tid = threadIdx.x;

  const float* x = path ? K : Q;
  const float* xbase = x + (((size_t)b * TT * HH + h) << 6);
#pragma unroll
  for (int it = 0; it < 2; ++it) {
    const int idx = (it << 9) + tid;   // 0..1023
    const int r = idx >> 4, c = (idx & 15) << 2;
    const float4 f4 = *(const float4*)&xbase[(size_t)(t0 + r) * 512 + c];
    xsT[c + 0][r] = f4.x; xsT[c + 1][r] = f4.y;
    xsT[c + 2][r] = f4.z; xsT[c + 3][r] = f4.w;
  }
  __syncthreads();

  const int lane = tid & 63;
  const int w = __builtin_amdgcn_readfirstlane(tid >> 6);   // 0..7
  float xv[64];
  float diag = 0.f;
#pragma unroll
  for (int c = 0; c < 64; ++c) { xv[c] = xsT[c][lane]; diag = fmaf(xv[c], xv[c], diag); }
  diag *= 0.0625f;   // 0.5*temp

  float lf[16];
  float mx = -3e30f;
  const int mbase = w << 4;
  for (int mm = 0; mm < 16; ++mm) {
    const float* pr = proj + ((mbase + mm) << 6);
    float a0 = 0.f, a1 = 0.f;
#pragma unroll
    for (int c = 0; c < 64; c += 2) {
      a0 = fmaf(xv[c], pr[c], a0);
      a1 = fmaf(xv[c + 1], pr[c + 1], a1);
    }
    const float v = fmaf(NORMALIZER, a0 + a1, -diag);
    lf[mm] = v;
    mx = fmaxf(mx, v);
  }
  Mh[lane][w] = mx;
  __syncthreads();
  float m0 = Mh[lane][0];
#pragma unroll
  for (int i = 1; i < 8; ++i) m0 = fmaxf(m0, Mh[lane][i]);

  float ov[16];
  if (path == 0) {
#pragma unroll
    for (int mm = 0; mm < 16; ++mm) ov[mm] = RSQRT_M * __expf(lf[mm] - m0);
    if (w == 0) qstab[(size_t)bh * TT + t0 + lane] = m0;
  } else {
#pragma unroll
    for (int mm = 0; mm < 16; ++mm) ov[mm] = __expf(lf[mm]);
    if (w == 0) {
      float bm = m0;
#pragma unroll
      for (int off = 1; off < 64; off <<= 1) bm = fmaxf(bm, __shfl_xor(bm, off));
      if (lane == 0) wtmax[(bh << 4) + rt] = bm;
    }
  }
  float* dst = (path ? kf : qp) + (((size_t)bh * TT + t0 + lane) << 7) + mbase;
#pragma unroll
  for (int q4 = 0; q4 < 4; ++q4)
    *(float4*)&dst[q4 << 2] =
        make_float4(ov[q4 * 4], ov[q4 * 4 + 1], ov[q4 * 4 + 2], ov[q4 * 4 + 3]);
}

// ---------------------------------------------------------------------------
// Kernel B: UNSCALED partial kv + ksum per 64-row s-tile. Grid 256. (R5/R7)
// ---------------------------------------------------------------------------
__global__ __launch_bounds__(256, 2) void kv_partial(
    const float* __restrict__ V, const float* __restrict__ kf,
    float* __restrict__ kvp, float* __restrict__ ksump)
{
  __shared__ __align__(16) float smem[64 * 132 + 64 * 68];
  float (*kp_s)[132] = (float(*)[132])smem;
  float (*vs)[68] = (float(*)[68])(smem + 64 * 132);

  const int bid = blockIdx.x;
  const int bh = bid >> 4, st = bid & 15;
  const int b = bh >> 3, h = bh & 7;
  const int tid = threadIdx.x;
  const int row0 = st << 6;
  const size_t base_kf = ((size_t)bh * TT + row0) << 7;

#pragma unroll
  for (int it = 0; it < 8; ++it) {
    const int idx = (it << 10) + (tid << 2);
    const int r = idx >> 7, c = idx & 127;
    *(float4*)&kp_s[r][c] = *(const float4*)&kf[base_kf + idx];
  }
#pragma unroll
  for (int it = 0; it < 4; ++it) {
    const int idx = (it << 10) + (tid << 2);
    const int r = idx >> 6, c = idx & 63;
    *(float4*)&vs[r][c] = *(const float4*)(V + ((((size_t)b * TT + row0 + r) * HH + h) << 6) + c);
  }
  __syncthreads();

  if (tid < 128) {
    float s = 0.f;
    for (int ss = 0; ss < 64; ++ss) s += kp_s[ss][tid];
    ksump[(bid << 7) + tid] = s;
  }

  const int h2 = tid >> 7;
  const int m0 = ((tid & 127) >> 3) << 3;
  const int d0 = (tid & 7) << 3;
  float acc[8][8];
#pragma unroll
  for (int i = 0; i < 8; ++i)
#pragma unroll
    for (int j = 0; j < 8; ++j) acc[i][j] = 0.f;

  const int s0 = h2 << 5;
  for (int ss = s0; ss < s0 + 32; ++ss) {
    const float4 k0v = *(const float4*)&kp_s[ss][m0];
    const float4 k1v = *(const float4*)&kp_s[ss][m0 + 4];
    const float4 v0v = *(const float4*)&vs[ss][d0];
    const float4 v1v = *(const float4*)&vs[ss][d0 + 4];
    const float km[8] = {k0v.x,k0v.y,k0v.z,k0v.w,k1v.x,k1v.y,k1v.z,k1v.w};
    const float vd[8] = {v0v.x,v0v.y,v0v.z,v0v.w,v1v.x,v1v.y,v1v.z,v1v.w};
#pragma unroll
    for (int i = 0; i < 8; ++i)
#pragma unroll
      for (int j = 0; j < 8; ++j) acc[i][j] = fmaf(km[i], vd[j], acc[i][j]);
  }
  __syncthreads();
  float (*kvm)[68] = (float(*)[68])smem;
  if (h2 == 0) {
#pragma unroll
    for (int i = 0; i < 8; ++i)
#pragma unroll
      for (int j = 0; j < 8; ++j) kvm[m0 + i][d0 + j] = acc[i][j];
  }
  __syncthreads();
  if (h2 == 1) {
#pragma unroll
    for (int i = 0; i < 8; ++i)
#pragma unroll
      for (int j = 0; j < 8; ++j) kvm[m0 + i][d0 + j] += acc[i][j];
  }
  __syncthreads();
  float* kvb = kvp + ((size_t)bid << 13);
#pragma unroll
  for (int it = 0; it < 8; ++it) {
    const int idx = (it << 10) + (tid << 2);
    const int m = idx >> 6, d = idx & 63;
    *(float4*)&kvb[idx] = make_float4(kvm[m][d], kvm[m][d + 1], kvm[m][d + 2], kvm[m][d + 3]);
  }
}

// ---------------------------------------------------------------------------
// Kernel B2: reduce 16 partials, apply scale. Grid 136. (R7)
// ---------------------------------------------------------------------------
__global__ __launch_bounds__(256, 4) void kv_reduce(
    const float* __restrict__ kvp, const float* __restrict__ ksump,
    const float* __restrict__ wtmax,
    float* __restrict__ kv, float* __restrict__ ksum)
{
  const int bid = blockIdx.x;
  const int tid = threadIdx.x;
  if (bid < 128) {
    const int g = (bid << 10) + (tid << 2);
    const int bh = g >> 13, idx = g & 8191;
    float kml = wtmax[bh << 4];
#pragma unroll
    for (int i = 1; i < 16; ++i) kml = fmaxf(kml, wtmax[(bh << 4) + i]);
    const float scale = RSQRT_M * __expf(-kml);
    float4 s = make_float4(0.f, 0.f, 0.f, 0.f);
#pragma unroll
    for (int p = 0; p < 16; ++p) {
      const float4 v = *(const float4*)&kvp[((((size_t)bh << 4) + p) << 13) + idx];
      s.x += v.x; s.y += v.y; s.z += v.z; s.w += v.w;
    }
    s.x *= scale; s.y *= scale; s.z *= scale; s.w *= scale;
    *(float4*)&kv[((size_t)bh << 13) + idx] = s;
  } else {
    const int g = ((bid - 128) << 8) + tid;
    const int bh = g >> 7, m = g & 127;
    float kml = wtmax[bh << 4];
#pragma unroll
    for (int i = 1; i < 16; ++i) kml = fmaxf(kml, wtmax[(bh << 4) + i]);
    const float scale = RSQRT_M * __expf(-kml);
    float s = 0.f;
#pragma unroll
    for (int p = 0; p < 16; ++p) s += ksump[(((bh << 4) + p) << 7) + m];
    ksum[(bh << 7) + m] = s * scale;
  }
}

// ---------------------------------------------------------------------------
// Kernel D: banded local attention via DOUBLE-BF16 (hi+lo, 3-product) MFMA.
// Grid 256 = 16 bh * 16 tiles(64 q, window 128). 78.6 KB LDS -> 2 blocks/CU.
// (verbatim R7 — passed at absmax 3.9e-3)
// ---------------------------------------------------------------------------
__global__ __launch_bounds__(256, 2) void band_kernel(
    const float* __restrict__ Q, const float* __restrict__ K,
    const float* __restrict__ V,
    const float* __restrict__ qp, const float* __restrict__ kp,
    const float* __restrict__ kv, const float* __restrict__ ksum,
    const float* __restrict__ qstab, const float* __restrict__ wtmax,
    float* __restrict__ out)
{
  __shared__ __align__(16) short smem[39168];
  __shared__ float pls_s[64];
  short* const qA_hi = smem;
  short* const qA_lo = smem + 4608;
  short* const B_hi  = smem + 9216;
  short* const B_lo  = smem + 18432;
  short* const kvT_hi = smem + 27648;
  short* const kvT_lo = smem + 33408;
  short* const VT_hi  = smem;            // phase C
  short* const VT_lo  = smem + 8704;
  short* const dots_hi = smem + 17408;
  short* const dots_lo = smem + 26112;

  const int g = blockIdx.x;
  const int lg = ((g & 7) << 5) | (g >> 3);          // XCD chunk swizzle (256 wgs)
  const int bh = lg >> 4, tile = lg & 15;
  const int b = bh >> 3, h = bh & 7;
  const int t0 = tile << 6;
  const int k0 = t0 - 32;
  const int tid = threadIdx.x;
  const int lane = tid & 63;
  const int wq = __builtin_amdgcn_readfirstlane(tid >> 6);

  float kml = wtmax[bh << 4];
#pragma unroll
  for (int i = 1; i < 16; ++i) kml = fmaxf(kml, wtmax[(bh << 4) + i]);
  const float kscale = RSQRT_M * __expf(-kml);

  const float* Qbase = Q + (((size_t)b * TT * HH + h) << 6);
  const float* Kbase = K + (((size_t)b * TT * HH + h) << 6);
  const float* Vbase = V + (((size_t)b * TT * HH + h) << 6);
  const float* qpb = qp + (((size_t)bh * TT) << 7);
  const float* kpb = kp + (((size_t)bh * TT) << 7);
  const float* kvb = kv + ((size_t)bh << 13);
  const float* ksb = ksum + (bh << 7);

  // ---- Phase A: stage q hi/lo (64x64) and K hi/lo (128x64), pls ----
#pragma unroll
  for (int it = 0; it < 4; ++it) {
    const int idx = (it << 8) + tid;
    const int r = idx >> 4, cc = (idx & 15) << 2;
    const float4 v = *(const float4*)&Qbase[(size_t)(t0 + r) * 512 + cc];
    short4 hi4, lo4;
    f2bf2(v.x, (unsigned short&)hi4.x, (unsigned short&)lo4.x);
    f2bf2(v.y, (unsigned short&)hi4.y, (unsigned short&)lo4.y);
    f2bf2(v.z, (unsigned short&)hi4.z, (unsigned short&)lo4.z);
    f2bf2(v.w, (unsigned short&)hi4.w, (unsigned short&)lo4.w);
    *(short4*)&qA_hi[r * 72 + cc] = hi4;
    *(short4*)&qA_lo[r * 72 + cc] = lo4;
  }
#pragma unroll
  for (int it = 0; it < 8; ++it) {
    const int idx = (it << 8) + tid;
    const int r = idx >> 4, cc = (idx & 15) << 2;
    const int tg = min(max(k0 + r, 0), TT - 1);
    const float4 v = *(const float4*)&Kbase[(size_t)tg * 512 + cc];
    short4 hi4, lo4;
    f2bf2(v.x, (unsigned short&)hi4.x, (unsigned short&)lo4.x);
    f2bf2(v.y, (unsigned short&)hi4.y, (unsigned short&)lo4.y);
    f2bf2(v.z, (unsigned short&)hi4.z, (unsigned short&)lo4.z);
    f2bf2(v.w, (unsigned short&)hi4.w, (unsigned short&)lo4.w);
    *(short4*)&B_hi[r * 72 + cc] = hi4;
    *(short4*)&B_lo[r * 72 + cc] = lo4;
  }
  if (tid < 64) pls_s[tid] = qstab[(size_t)bh * TT + t0 + tid] + kml;
  __syncthreads();

  // ---- GEMM1: S = q . K^T (3-product) ----
  f32x4 C1[8];
#pragma unroll
  for (int nt = 0; nt < 8; ++nt) C1[nt] = (f32x4){0.f, 0.f, 0.f, 0.f};
  {
    const short8v qh0 = ldfrag(qA_hi, 72, wq << 4, 0, lane);
    const short8v qh1 = ldfrag(qA_hi, 72, wq << 4, 32, lane);
    const short8v ql0 = ldfrag(qA_lo, 72, wq << 4, 0, lane);
    const short8v ql1 = ldfrag(qA_lo, 72, wq << 4, 32, lane);
#pragma unroll
    for (int nt = 0; nt < 8; ++nt) {
      const short8v bh0 = ldfrag(B_hi, 72, nt << 4, 0, lane);
      const short8v bh1 = ldfrag(B_hi, 72, nt << 4, 32, lane);
      C1[nt] = MFMA_BF16(qh0, bh0, C1[nt], 0, 0, 0);
      C1[nt] = MFMA_BF16(qh1, bh1, C1[nt], 0, 0, 0);
      C1[nt] = MFMA_BF16(qh0, ldfrag(B_lo, 72, nt << 4, 0, lane), C1[nt], 0, 0, 0);
      C1[nt] = MFMA_BF16(qh1, ldfrag(B_lo, 72, nt << 4, 32, lane), C1[nt], 0, 0, 0);
      C1[nt] = MFMA_BF16(ql0, bh0, C1[nt], 0, 0, 0);
      C1[nt] = MFMA_BF16(ql1, bh1, C1[nt], 0, 0, 0);
    }
  }
  __syncthreads();

  // ---- GEMM2 (q' . kp^T) + qkv (q' . kv) + qk1, two 64-m chunks ----
  f32x4 C2[8], C3[5];
#pragma unroll
  for (int nt = 0; nt < 8; ++nt) C2[nt] = (f32x4){0.f, 0.f, 0.f, 0.f};
#pragma unroll
  for (int nt = 0; nt < 5; ++nt) C3[nt] = (f32x4){0.f, 0.f, 0.f, 0.f};

#pragma unroll 1
  for (int c = 0; c < 2; ++c) {
    const int co = c << 6;
    // qp chunk hi/lo -> qA planes
#pragma unroll
    for (int it = 0; it < 4; ++it) {
      const int idx = (it << 8) + tid;
      const int r = idx >> 4, cc = (idx & 15) << 2;
      const float4 v = *(const float4*)&qpb[((size_t)(t0 + r) << 7) + co + cc];
      short4 hi4, lo4;
      f2bf2(v.x, (unsigned short&)hi4.x, (unsigned short&)lo4.x);
      f2bf2(v.y, (unsigned short&)hi4.y, (unsigned short&)lo4.y);
      f2bf2(v.z, (unsigned short&)hi4.z, (unsigned short&)lo4.z);
      f2bf2(v.w, (unsigned short&)hi4.w, (unsigned short&)lo4.w);
      *(short4*)&qA_hi[r * 72 + cc] = hi4;
      *(short4*)&qA_lo[r * 72 + cc] = lo4;
    }
    // kp chunk hi/lo -> B planes
#pragma unroll
    for (int it = 0; it < 8; ++it) {
      const int idx = (it << 8) + tid;
      const int r = idx >> 4, cc = (idx & 15) << 2;
      const int tg = min(max(k0 + r, 0), TT - 1);
      const float4 v = *(const float4*)&kpb[((size_t)tg << 7) + co + cc];
      short4 hi4, lo4;
      f2bf2(v.x, (unsigned short&)hi4.x, (unsigned short&)lo4.x);
      f2bf2(v.y, (unsigned short&)hi4.y, (unsigned short&)lo4.y);
      f2bf2(v.z, (unsigned short&)hi4.z, (unsigned short&)lo4.z);
      f2bf2(v.w, (unsigned short&)hi4.w, (unsigned short&)lo4.w);
      *(short4*)&B_hi[r * 72 + cc] = hi4;
      *(short4*)&B_lo[r * 72 + cc] = lo4;
    }
    // kv^T chunk hi/lo -> kvT planes rows 0..63 (row=d, col=m_local)
    {
      const int mloc = tid >> 2, db = (tid & 3) << 4;
      const float4* kr = (const float4*)(kvb + ((co + mloc) << 6) + db);
#pragma unroll
      for (int i2 = 0; i2 < 4; ++i2) {
        const float4 v = kr[i2];
        const int dr = db + (i2 << 2);
        unsigned short hs, ls;
        f2bf2(v.x, hs, ls); kvT_hi[(dr + 0) * 72 + mloc] = hs; kvT_lo[(dr + 0) * 72 + mloc] = ls;
        f2bf2(v.y, hs, ls); kvT_hi[(dr + 1) * 72 + mloc] = hs; kvT_lo[(dr + 1) * 72 + mloc] = ls;
        f2bf2(v.z, hs, ls); kvT_hi[(dr + 2) * 72 + mloc] = hs; kvT_lo[(dr + 2) * 72 + mloc] = ls;
        f2bf2(v.w, hs, ls); kvT_hi[(dr + 3) * 72 + mloc] = hs; kvT_lo[(dr + 3) * 72 + mloc] = ls;
      }
    }
    // ksum hi/lo in kvT_hi rows 64/65; kvT_lo rows 64/65 zeroed
    if (tid < 64) {
      const float xk = ksb[co + tid];
      unsigned short hs, ls;
      f2bf2(xk, hs, ls);
      kvT_hi[64 * 72 + tid] = hs;
      kvT_hi[65 * 72 + tid] = ls;
      kvT_lo[64 * 72 + tid] = 0;
      kvT_lo[65 * 72 + tid] = 0;
    }
    __syncthreads();

    const short8v ph0 = ldfrag(qA_hi, 72, wq << 4, 0, lane);
    const short8v ph1 = ldfrag(qA_hi, 72, wq << 4, 32, lane);
    const short8v pl0 = ldfrag(qA_lo, 72, wq << 4, 0, lane);
    const short8v pl1 = ldfrag(qA_lo, 72, wq << 4, 32, lane);
#pragma unroll
    for (int nt = 0; nt < 8; ++nt) {
      const short8v bh0 = ldfrag(B_hi, 72, nt << 4, 0, lane);
      const short8v bh1 = ldfrag(B_hi, 72, nt << 4, 32, lane);
      C2[nt] = MFMA_BF16(ph0, bh0, C2[nt], 0, 0, 0);
      C2[nt] = MFMA_BF16(ph1, bh1, C2[nt], 0, 0, 0);
      C2[nt] = MFMA_BF16(ph0, ldfrag(B_lo, 72, nt << 4, 0, lane), C2[nt], 0, 0, 0);
      C2[nt] = MFMA_BF16(ph1, ldfrag(B_lo, 72, nt << 4, 32, lane), C2[nt], 0, 0, 0);
      C2[nt] = MFMA_BF16(pl0, bh0, C2[nt], 0, 0, 0);
      C2[nt] = MFMA_BF16(pl1, bh1, C2[nt], 0, 0, 0);
    }
#pragma unroll
    for (int nt = 0; nt < 5; ++nt) {
      const short8v kh0 = ldfrag(kvT_hi, 72, nt << 4, 0, lane);
      const short8v kh1 = ldfrag(kvT_hi, 72, nt << 4, 32, lane);
      C3[nt] = MFMA_BF16(ph0, kh0, C3[nt], 0, 0, 0);
      C3[nt] = MFMA_BF16(ph1, kh1, C3[nt], 0, 0, 0);
      C3[nt] = MFMA_BF16(ph0, ldfrag(kvT_lo, 72, nt << 4, 0, lane), C3[nt], 0, 0, 0);
      C3[nt] = MFMA_BF16(ph1, ldfrag(kvT_lo, 72, nt << 4, 32, lane), C3[nt], 0, 0, 0);
      C3[nt] = MFMA_BF16(pl0, kh0, C3[nt], 0, 0, 0);
      C3[nt] = MFMA_BF16(pl1, kh1, C3[nt], 0, 0, 0);
    }
    __syncthreads();
  }

  // ---- Phase C: stage V^T hi/lo (rows d, cols j, LD 136) ----
  {
    const int jl = tid >> 1, db = (tid & 1) << 5;
    const int tg = min(max(k0 + jl, 0), TT - 1);
    const float4* vr = (const float4*)&Vbase[(size_t)tg * 512 + db];
#pragma unroll
    for (int i2 = 0; i2 < 8; ++i2) {
      const float4 v = vr[i2];
      const int dr = db + (i2 << 2);
      unsigned short hs, ls;
      f2bf2(v.x, hs, ls); VT_hi[(dr + 0) * 136 + jl] = hs; VT_lo[(dr + 0) * 136 + jl] = ls;
      f2bf2(v.y, hs, ls); VT_hi[(dr + 1) * 136 + jl] = hs; VT_lo[(dr + 1) * 136 + jl] = ls;
      f2bf2(v.z, hs, ls); VT_hi[(dr + 2) * 136 + jl] = hs; VT_lo[(dr + 2) * 136 + jl] = ls;
      f2bf2(v.w, hs, ls); VT_hi[(dr + 3) * 136 + jl] = hs; VT_lo[(dr + 3) * 136 + jl] = ls;
    }
  }

  // ---- P3: per-lane softmax / log-norm, dots hi/lo -> LDS ----
  float psr[4];
  const int lrow = (lane >> 4) << 2;
  const int lcol = lane & 15;
#pragma unroll
  for (int r = 0; r < 4; ++r) {
    const int ql = (wq << 4) + lrow + r;
    float qkt[8], dpt[8];
    float mx = -3e30f;
#pragma unroll
    for (int nt = 0; nt < 8; ++nt) {
      const int kr = (nt << 4) + lcol;
      const int j = kr - ql;
      const int gk = k0 + kr;
      const bool vv = (j >= 0) && (j < 64) && (gk >= 0) && (gk < TT);
      qkt[nt] = vv ? TEMP * C1[nt][r] : NEGINF;
      dpt[nt] = vv ? kscale * C2[nt][r] : 0.f;
      mx = fmaxf(mx, qkt[nt]);
    }
    mx = fmaxf(mx, __shfl_xor(mx, 1));
    mx = fmaxf(mx, __shfl_xor(mx, 2));
    mx = fmaxf(mx, __shfl_xor(mx, 4));
    mx = fmaxf(mx, __shfl_xor(mx, 8));
    float se = 0.f, dps = 0.f;
#pragma unroll
    for (int nt = 0; nt < 8; ++nt) {
      se += __expf(qkt[nt] - mx);
      dps += dpt[nt];
    }
    se += __shfl_xor(se, 1); se += __shfl_xor(se, 2);
    se += __shfl_xor(se, 4); se += __shfl_xor(se, 8);
    dps += __shfl_xor(dps, 1); dps += __shfl_xor(dps, 2);
    dps += __shfl_xor(dps, 4); dps += __shfl_xor(dps, 8);
    const float qk1 = __shfl(C3[4][r], lane & 48) + __shfl(C3[4][r], (lane & 48) + 1);

    const float pls = pls_s[ql];
    const float lse = mx + __logf(se);
    const float lr = fmaxf(qk1 - dps, 1e-24f);
    const float lrl = __logf(lr) + pls;
    const float aa = fmaxf(lse, lrl), bb = fminf(lse, lrl);
    const float ln = aa + log1pf(__expf(bb - aa));
    psr[r] = __expf(pls - ln);
#pragma unroll
    for (int nt = 0; nt < 8; ++nt) {
      const float d = __expf(qkt[nt] - ln) - dpt[nt] * psr[r];
      unsigned short hs, ls;
      f2bf2(d, hs, ls);
      dots_hi[ql * 136 + (nt << 4) + lcol] = hs;
      dots_lo[ql * 136 + (nt << 4) + lcol] = ls;
    }
  }
  __syncthreads();

  // ---- PV: out_local = dots . V (3-product) + epilogue ----
  f32x4 D4[4];
#pragma unroll
  for (int nt = 0; nt < 4; ++nt) D4[nt] = (f32x4){0.f, 0.f, 0.f, 0.f};
#pragma unroll
  for (int kk = 0; kk < 4; ++kk) {
    const short8v adh = ldfrag(dots_hi, 136, wq << 4, kk << 5, lane);
    const short8v adl = ldfrag(dots_lo, 136, wq << 4, kk << 5, lane);
#pragma unroll
    for (int nt = 0; nt < 4; ++nt) {
      const short8v vh = ldfrag(VT_hi, 136, nt << 4, kk << 5, lane);
      D4[nt] = MFMA_BF16(adh, vh, D4[nt], 0, 0, 0);
      D4[nt] = MFMA_BF16(adh, ldfrag(VT_lo, 136, nt << 4, kk << 5, lane), D4[nt], 0, 0, 0);
      D4[nt] = MFMA_BF16(adl, vh, D4[nt], 0, 0, 0);
    }
  }
#pragma unroll
  for (int nt = 0; nt < 4; ++nt) {
#pragma unroll
    for (int r = 0; r < 4; ++r) {
      const int ql = (wq << 4) + lrow + r;
      const float val = D4[nt][r] + C3[nt][r] * psr[r];
      out[((((size_t)b * TT + t0 + ql) * HH + h) << 6) + (nt << 4) + lcol] = val;
    }
  }
}

extern "C" void kernel_launch(void* const* d_in, const int* in_sizes, int n_in,
                              void* d_out, int out_size, void* d_ws, size_t ws_size,
                              hipStream_t stream) {
  (void)in_sizes; (void)n_in; (void)out_size; (void)ws_size;
  const float* Q    = (const float*)d_in[0];
  const float* K    = (const float*)d_in[1];
  const float* V    = (const float*)d_in[2];
  const float* proj = (const float*)d_in[3];
  float* out = (float*)d_out;
  char* ws = (char*)d_ws;

  float* qp    = (float*)(ws + OFF_QP);
  float* kf    = (float*)(ws + OFF_KF);
  float* kvp   = (float*)(ws + OFF_KVP);
  float* kv    = (float*)(ws + OFF_KV);
  float* ksum  = (float*)(ws + OFF_KSUM);
  float* qstab = (float*)(ws + OFF_QSTAB);
  float* ksump = (float*)(ws + OFF_KSUMP);
  float* wtmax = (float*)(ws + OFF_WTMAX);

  feat_kernel<<<512, 512, 0, stream>>>(Q, K, proj, qp, kf, qstab, wtmax);
  kv_partial<<<256, 256, 0, stream>>>(V, kf, kvp, ksump);
  kv_reduce<<<136, 256, 0, stream>>>(kvp, ksump, wtmax, kv, ksum);
  band_kernel<<<256, 256, 0, stream>>>(Q, K, V, qp, kf, kv, ksum, qstab, wtmax, out);
}